// Round 1
// baseline (141.660 us; speedup 1.0000x reference)
//
#include <hip/hip_runtime.h>
#include <stdint.h>

#define BATCH 4
#define NPTS 4096
#define KNN 11            // K+1 neighbors including self
#define LPQ 16            // lanes per query
#define QPB 32            // queries per block (2 per thread: i and i+16)
#define CHUNK 1024        // LDS candidate chunk
#define NCHUNK (NPTS / CHUNK)     // 4
#define CPL (CHUNK / LPQ)         // 64 candidates per lane per chunk
#define BUFN 10           // per-lane qualifier buffer slots (per query)
#define SENT_BITS 0x433FFFFFFFFFFFFFll

// monotone float -> uint mapping (ascending)
__device__ __forceinline__ unsigned sortable_f32(float d) {
    unsigned b = __float_as_uint(d);
    unsigned m = (unsigned)(((int)b) >> 31) | 0x80000000u;
    return b ^ m;
}

// drain qualifier buffer through the f64 insertion network (r11 verbatim,
// parameterized). Caller resets cnt. Wave-uniform early-out preserved.
__device__ __forceinline__ void drain_buf(const unsigned long long* buf,
                                          int tid, int cnt, double* kd) {
#pragma clang fp contract(off)
    for (int k = 0; k < BUFN; ++k) {
        if (!__any(cnt > k)) break;     // early out (late flushes)
        unsigned long long kb = buf[k * 256 + tid];
        double key = (k < cnt) ? __longlong_as_double(kb)
                               : __longlong_as_double(SENT_BITS);
#pragma unroll
        for (int kk = KNN-1; kk > 0; --kk) {
            double mn = fmin(kd[kk], key);
            kd[kk] = fmax(kd[kk-1], mn);
        }
        kd[0] = fmin(kd[0], key);
    }
}

// exact tau pop-merge over the 16-lane query group (r13 verbatim).
__device__ __forceinline__ float tau_update(const double* kd) {
#pragma clang fp contract(off)
    double tmp[KNN];
#pragma unroll
    for (int k = 0; k < KNN; ++k) tmp[k] = kd[k];
    double h = tmp[0];
#pragma unroll
    for (int r = 0; r < KNN; ++r) {
        h = tmp[0];
#pragma unroll
        for (int m = 1; m <= 8; m <<= 1)
            h = fmin(h, __shfl_xor(h, m, LPQ));
        bool own = (__double_as_longlong(tmp[0]) ==
                    __double_as_longlong(h));
#pragma unroll
        for (int t2 = 0; t2 < KNN-1; ++t2)
            tmp[t2] = own ? tmp[t2+1] : tmp[t2];
        tmp[KNN-1] = own ? __longlong_as_double(SENT_BITS)
                         : tmp[KNN-1];
    }
    unsigned tau_u = (unsigned)((unsigned long long)
                                __double_as_longlong(h) >> 12);
    // unsortable: real d2 keys have top bit set
    return __uint_as_float(tau_u ^ 0x80000000u);
}

// destructive 16-lane merge (r8 verbatim) + fused MLP, per query.
__device__ __forceinline__ void merge_mlp_store(
    double* kd, float xq, float yq, float zq,
    const float* __restrict__ pb, const float* __restrict__ vb,
    const float* __restrict__ W1, const float* __restrict__ b1,
    const float* __restrict__ W2, const float* __restrict__ b2,
    const float* __restrict__ W3, const float* __restrict__ b3,
    float c0i, float c1i, float c2i,
    int p, int b, int i, float* __restrict__ out)
{
#pragma clang fp contract(off)
    unsigned res[KNN];
#pragma unroll
    for (int r = 0; r < KNN; ++r) {
        double h = kd[0];
#pragma unroll
        for (int m = 1; m <= 8; m <<= 1)
            h = fmin(h, __shfl_xor(h, m, LPQ));
        long long hb = __double_as_longlong(h);
        res[r] = (unsigned)(hb & 0xFFF);
        bool own = (__double_as_longlong(kd[0]) == hb);
#pragma unroll
        for (int t = 0; t < KNN-1; ++t) kd[t] = own ? kd[t+1] : kd[t];
        kd[KNN-1] = own ? __longlong_as_double(SENT_BITS) : kd[KNN-1];
    }

    // ---------- fused MLP, lane-parallel, BIT-IDENTICAL to r8 ----------
    const float* w0 = W1 + (2*p)   * 66;
    const float* w1 = W1 + (2*p+1) * 66;
    float a0 = b1[2*p], a1 = b1[2*p+1];
#pragma unroll
    for (int k = 1; k < KNN; ++k) {       // ff 0..29: relative positions
        const float* pn = pb + 3*(int)res[k];
        float dx = pn[0] - xq, dy = pn[1] - yq, dz = pn[2] - zq;
        int ff = 3*(k-1);
        a0 = fmaf(dx, w0[ff+0], a0); a1 = fmaf(dx, w1[ff+0], a1);
        a0 = fmaf(dy, w0[ff+1], a0); a1 = fmaf(dy, w1[ff+1], a1);
        a0 = fmaf(dz, w0[ff+2], a0); a1 = fmaf(dz, w1[ff+2], a1);
    }
#pragma unroll
    for (int k = 0; k < KNN; ++k) {       // ff 30..62: velocities
        const float* vn = vb + 3*(int)res[k];
        int ff = 30 + 3*k;
        a0 = fmaf(vn[0], w0[ff+0], a0); a1 = fmaf(vn[0], w1[ff+0], a1);
        a0 = fmaf(vn[1], w0[ff+1], a0); a1 = fmaf(vn[1], w1[ff+1], a1);
        a0 = fmaf(vn[2], w0[ff+2], a0); a1 = fmaf(vn[2], w1[ff+2], a1);
    }
    a0 = fmaf(c0i, w0[63], a0); a1 = fmaf(c0i, w1[63], a1);
    a0 = fmaf(c1i, w0[64], a0); a1 = fmaf(c1i, w1[64], a1);
    a0 = fmaf(c2i, w0[65], a0); a1 = fmaf(c2i, w1[65], a1);

    float h2 = b2[p];
    const float* w2 = W2 + p * 32;
#pragma unroll
    for (int ii = 0; ii < 32; ++ii) {
        float h1v = __shfl((ii & 1) ? a1 : a0, ii >> 1, LPQ);
        h2 = fmaf(h1v, w2[ii], h2);
    }
    int o3 = p < 6 ? p : 0;
    float po = b3[o3];
    const float* w3 = W3 + o3 * 16;
#pragma unroll
    for (int ii = 0; ii < 16; ++ii) {
        float h2v = __shfl(h2, ii, LPQ);
        po = fmaf(h2v, w3[ii], po);
    }
    float resid = (p == 0) ? xq : (p == 1) ? yq : (p == 2) ? zq : 0.0f;
    po += resid;                           // residual on first 3 channels

    if (p < 6)
        out[((size_t)b * NPTS + (size_t)i) * 6 + p] = po;
}

// Fused exact 11-NN + MLP. FROZEN d2 arithmetic (verified r4-r12):
//   sq_j = fl(fl(x2)+fl(y2)) + fl(z2); dot = fma chain; d2 = fl(si+sj)-fl(2t).
// r14 = r13 + ONE structural change: Q=2 queries per thread. Each candidate
// float4 is read from LDS ONCE and feeds BOTH queries' (identical, frozen)
// d2 chains -> wave-level ds_read_b128 count halves (the ~20 us LDS-pipe
// floor of r13's scan). Per-query top-k state/flush/tau/merge/MLP logic is
// duplicated verbatim, so selection + MLP arithmetic is unchanged per query.
__global__ __launch_bounds__(256, 2) void fused_kernel(
    const float* __restrict__ pos, const float* __restrict__ vel,
    const float* __restrict__ initc,
    const float* __restrict__ W1, const float* __restrict__ b1,
    const float* __restrict__ W2, const float* __restrict__ b2,
    const float* __restrict__ W3, const float* __restrict__ b3,
    float* __restrict__ out)
{
#pragma clang fp contract(off)
    // skewed float4 (x,y,z,sq): idx + (idx>>6) -> partitions offset by 16B
    __shared__ float4 sp[CHUNK + LPQ];
    // slot-major lane-private buffers: lanes 8B apart -> 2-way -> free
    __shared__ unsigned long long bufA[BUFN * 256];
    __shared__ unsigned long long bufB[BUFN * 256];

    int b    = blockIdx.x >> 7;           // 128 blocks per batch
    int qblk = blockIdx.x & 127;
    int tid  = threadIdx.x;
    const float* pb = pos + (size_t)b * NPTS * 3;

    int q = tid >> 4, p = tid & 15;
    int iA = qblk * QPB + q;              // query A
    int iB = iA + 16;                     // query B

    float xqA = pb[3*iA], yqA = pb[3*iA+1], zqA = pb[3*iA+2];
    float sqqA = xqA*xqA + yqA*yqA + zqA*zqA;  // contract(off): np sum order
    float xqB = pb[3*iB], yqB = pb[3*iB+1], zqB = pb[3*iB+2];
    float sqqB = xqB*xqB + yqB*yqB + zqB*zqB;

    double kdA[KNN], kdB[KNN];
#pragma unroll
    for (int k = 0; k < KNN; ++k) {
        kdA[k] = __longlong_as_double(SENT_BITS);
        kdB[k] = __longlong_as_double(SENT_BITS);
    }
    float tauA = __builtin_inff(), tauB = __builtin_inff();
    int cntA = 0, cntB = 0, nfA = 0, nfB = 0;

    for (int c = 0; c < NCHUNK; ++c) {
        if (c) __syncthreads();
        for (int j = tid; j < CHUNK; j += 256) {
            int g = c * CHUNK + j;
            float x = pb[3*g], y = pb[3*g+1], z = pb[3*g+2];
            float sq = x*x + y*y + z*z;   // FROZEN staged sq
            sp[j + (j >> 6)] = make_float4(x, y, z, sq);
        }
        __syncthreads();

        int sbase = p * (CPL + 1);
        int jg    = c * CHUNK + p * CPL;
        for (int jl = 0; jl < CPL; jl += 4) {
            // 4 back-to-back LDS reads; 8 independent d2 chains (2 queries)
            float4 c0 = sp[sbase + jl + 0];
            float4 c1 = sp[sbase + jl + 1];
            float4 c2 = sp[sbase + jl + 2];
            float4 c3 = sp[sbase + jl + 3];

            float tA0 = xqA*c0.x, tA1 = xqA*c1.x, tA2 = xqA*c2.x, tA3 = xqA*c3.x;
            float tB0 = xqB*c0.x, tB1 = xqB*c1.x, tB2 = xqB*c2.x, tB3 = xqB*c3.x;
            tA0 = fmaf(yqA, c0.y, tA0); tA1 = fmaf(yqA, c1.y, tA1);
            tA2 = fmaf(yqA, c2.y, tA2); tA3 = fmaf(yqA, c3.y, tA3);
            tB0 = fmaf(yqB, c0.y, tB0); tB1 = fmaf(yqB, c1.y, tB1);
            tB2 = fmaf(yqB, c2.y, tB2); tB3 = fmaf(yqB, c3.y, tB3);
            tA0 = fmaf(zqA, c0.z, tA0); tA1 = fmaf(zqA, c1.z, tA1);
            tA2 = fmaf(zqA, c2.z, tA2); tA3 = fmaf(zqA, c3.z, tA3);
            tB0 = fmaf(zqB, c0.z, tB0); tB1 = fmaf(zqB, c1.z, tB1);
            tB2 = fmaf(zqB, c2.z, tB2); tB3 = fmaf(zqB, c3.z, tB3);
            float dA0 = (sqqA + c0.w) - 2.0f*tA0;
            float dA1 = (sqqA + c1.w) - 2.0f*tA1;
            float dA2 = (sqqA + c2.w) - 2.0f*tA2;
            float dA3 = (sqqA + c3.w) - 2.0f*tA3;
            float dB0 = (sqqB + c0.w) - 2.0f*tB0;
            float dB1 = (sqqB + c1.w) - 2.0f*tB1;
            float dB2 = (sqqB + c2.w) - 2.0f*tB2;
            float dB3 = (sqqB + c3.w) - 2.0f*tB3;

            // f32 gates (== u32 gate by monotonicity); pack only on accept
#pragma unroll
            for (int s = 0; s < 4; ++s) {
                float dvA = s == 0 ? dA0 : s == 1 ? dA1 : s == 2 ? dA2 : dA3;
                if (dvA <= tauA) {
                    unsigned u  = sortable_f32(dvA);
                    unsigned lo = (u << 12) | (unsigned)(jg + jl + s);
                    unsigned hi = 0x43300000u | (u >> 20);
                    bufA[cntA * 256 + tid] =
                        ((unsigned long long)hi << 32) | (unsigned long long)lo;
                    ++cntA;
                }
                float dvB = s == 0 ? dB0 : s == 1 ? dB1 : s == 2 ? dB2 : dB3;
                if (dvB <= tauB) {
                    unsigned u  = sortable_f32(dvB);
                    unsigned lo = (u << 12) | (unsigned)(jg + jl + s);
                    unsigned hi = 0x43300000u | (u >> 20);
                    bufB[cntB * 256 + tid] =
                        ((unsigned long long)hi << 32) | (unsigned long long)lo;
                    ++cntB;
                }
            }

            int over = (cntA > BUFN - 4) | (cntB > BUFN - 4);
            if (__any(over)) {
                // independent per-buffer flushes (overflow-safe per query)
                if (__any(cntA > BUFN - 4)) {
                    drain_buf(bufA, tid, cntA, kdA);
                    cntA = 0;
                    if (nfA < 3) { ++nfA; tauA = tau_update(kdA); }
                }
                if (__any(cntB > BUFN - 4)) {
                    drain_buf(bufB, tid, cntB, kdB);
                    cntB = 0;
                    if (nfB < 3) { ++nfB; tauB = tau_update(kdB); }
                }
            }
        }
    }

    // final drains
    drain_buf(bufA, tid, cntA, kdA);
    drain_buf(bufB, tid, cntB, kdB);

    const float* vb = vel + (size_t)b * NPTS * 3;
    float c0i = initc[b*3+0], c1i = initc[b*3+1], c2i = initc[b*3+2];

    // merge+MLP for A first (kills kdA/resA liveness), then B
    merge_mlp_store(kdA, xqA, yqA, zqA, pb, vb, W1, b1, W2, b2, W3, b3,
                    c0i, c1i, c2i, p, b, iA, out);
    merge_mlp_store(kdB, xqB, yqB, zqB, pb, vb, W1, b1, W2, b2, W3, b3,
                    c0i, c1i, c2i, p, b, iB, out);
}

extern "C" void kernel_launch(void* const* d_in, const int* in_sizes, int n_in,
                              void* d_out, int out_size, void* d_ws, size_t ws_size,
                              hipStream_t stream) {
    const float* pos   = (const float*)d_in[0];
    const float* vel   = (const float*)d_in[1];
    const float* initc = (const float*)d_in[2];
    const float* W1    = (const float*)d_in[3];
    const float* b1    = (const float*)d_in[4];
    const float* W2    = (const float*)d_in[5];
    const float* b2    = (const float*)d_in[6];
    const float* W3    = (const float*)d_in[7];
    const float* b3    = (const float*)d_in[8];
    float* out = (float*)d_out;

    fused_kernel<<<dim3(BATCH * (NPTS / QPB)), dim3(256), 0, stream>>>(
        pos, vel, initc, W1, b1, W2, b2, W3, b3, out);
}

// Round 2
// 132.097 us; speedup vs baseline: 1.0724x; 1.0724x over previous
//
#include <hip/hip_runtime.h>
#include <stdint.h>

#define BATCH 4
#define NPTS 4096
#define KNN 11            // K+1 neighbors including self
#define LPQ 16            // lanes per query
#define QPB 16            // queries per block
#define CHUNK 1024        // LDS candidate chunk
#define NCHUNK (NPTS / CHUNK)     // 4
#define CPL (CHUNK / LPQ)         // 64 candidates per lane per chunk
#define BUFN 10           // per-lane qualifier buffer slots
#define SENT_BITS 0x433FFFFFFFFFFFFFll

// monotone float -> uint mapping (ascending)
__device__ __forceinline__ unsigned sortable_f32(float d) {
    unsigned b = __float_as_uint(d);
    unsigned m = (unsigned)(((int)b) >> 31) | 0x80000000u;
    return b ^ m;
}

// Fused exact 11-NN + MLP. FROZEN d2 arithmetic (verified r4-r12):
//   sq_j = fl(fl(x2)+fl(y2)) + fl(z2); dot = fma chain; d2 = fl(si+sj)-fl(2t).
// top-k ascending d2, ties -> lower index; key = double with bits
// 0x433<<52 | sortable(d2)<<12 | j  (f64 order == (d2 asc, j asc)).
// r15 = r13 skeleton (Q=1 restored after r14's occupancy regression) + two
// scan-core changes:
//  (1) 8-wide candidate batching: 8 ds_read_b128 + 8 independent d2 chains
//      per iter -> deeper MLP(memory-level-parallelism) to hide ds latency
//      at unchanged occupancy (r14 showed the kernel is latency-bound, not
//      LDS-throughput-bound).
//  (2) d2 via fmaf(-2,t,s): fl(s - fl(2t)) == fl(s - 2t) since 2t is exact
//      -> bit-identical, one less VALU op per eval.
// Flush threshold cnt > BUFN-8 so 8 packs always fit in the 10-slot buffer.
__global__ __launch_bounds__(256, 4) void fused_kernel(
    const float* __restrict__ pos, const float* __restrict__ vel,
    const float* __restrict__ initc,
    const float* __restrict__ W1, const float* __restrict__ b1,
    const float* __restrict__ W2, const float* __restrict__ b2,
    const float* __restrict__ W3, const float* __restrict__ b3,
    float* __restrict__ out)
{
#pragma clang fp contract(off)
    // skewed float4 (x,y,z,sq): idx + (idx>>6) -> partitions offset by 16B
    __shared__ float4 sp[CHUNK + LPQ];
    // slot-major lane-private buffers: lanes 8B apart -> 2-way -> free
    __shared__ unsigned long long buf[BUFN * 256];

    int b    = blockIdx.x >> 8;           // 256 blocks per batch
    int qblk = blockIdx.x & 255;
    int tid  = threadIdx.x;
    const float* pb = pos + (size_t)b * NPTS * 3;

    int q = tid >> 4, p = tid & 15;
    int i = qblk * QPB + q;               // query index within batch

    float xq = pb[3*i], yq = pb[3*i+1], zq = pb[3*i+2];
    float sqq = xq*xq + yq*yq + zq*zq;    // contract(off): np sum order

    double kd[KNN];
#pragma unroll
    for (int k = 0; k < KNN; ++k) kd[k] = __longlong_as_double(SENT_BITS);
    float tau_f = __builtin_inff();       // stale-conservative gate threshold
    int cnt = 0, nflush = 0;

    for (int c = 0; c < NCHUNK; ++c) {
        if (c) __syncthreads();
        for (int j = tid; j < CHUNK; j += 256) {
            int g = c * CHUNK + j;
            float x = pb[3*g], y = pb[3*g+1], z = pb[3*g+2];
            float sq = x*x + y*y + z*z;   // FROZEN staged sq
            sp[j + (j >> 6)] = make_float4(x, y, z, sq);
        }
        __syncthreads();

        int sbase = p * (CPL + 1);
        int jg    = c * CHUNK + p * CPL;
        for (int jl = 0; jl < CPL; jl += 8) {
            // 8 back-to-back LDS reads + 8 independent d2 chains (deep MLP)
            float4 c0 = sp[sbase + jl + 0];
            float4 c1 = sp[sbase + jl + 1];
            float4 c2 = sp[sbase + jl + 2];
            float4 c3 = sp[sbase + jl + 3];
            float4 c4 = sp[sbase + jl + 4];
            float4 c5 = sp[sbase + jl + 5];
            float4 c6 = sp[sbase + jl + 6];
            float4 c7 = sp[sbase + jl + 7];
            float t0 = xq*c0.x, t1 = xq*c1.x, t2 = xq*c2.x, t3 = xq*c3.x;
            float t4 = xq*c4.x, t5 = xq*c5.x, t6 = xq*c6.x, t7 = xq*c7.x;
            t0 = fmaf(yq, c0.y, t0); t1 = fmaf(yq, c1.y, t1);
            t2 = fmaf(yq, c2.y, t2); t3 = fmaf(yq, c3.y, t3);
            t4 = fmaf(yq, c4.y, t4); t5 = fmaf(yq, c5.y, t5);
            t6 = fmaf(yq, c6.y, t6); t7 = fmaf(yq, c7.y, t7);
            t0 = fmaf(zq, c0.z, t0); t1 = fmaf(zq, c1.z, t1);
            t2 = fmaf(zq, c2.z, t2); t3 = fmaf(zq, c3.z, t3);
            t4 = fmaf(zq, c4.z, t4); t5 = fmaf(zq, c5.z, t5);
            t6 = fmaf(zq, c6.z, t6); t7 = fmaf(zq, c7.z, t7);
            // fl((sqq+cw) - fl(2t)) == fl((sqq+cw) - 2t): 2t exact -> fma ok
            float d0 = fmaf(-2.0f, t0, sqq + c0.w);
            float d1 = fmaf(-2.0f, t1, sqq + c1.w);
            float d2 = fmaf(-2.0f, t2, sqq + c2.w);
            float d3 = fmaf(-2.0f, t3, sqq + c3.w);
            float d4 = fmaf(-2.0f, t4, sqq + c4.w);
            float d5 = fmaf(-2.0f, t5, sqq + c5.w);
            float d6 = fmaf(-2.0f, t6, sqq + c6.w);
            float d7 = fmaf(-2.0f, t7, sqq + c7.w);

            // f32 gate (== u32 gate by monotonicity); pack only on accept
#pragma unroll
            for (int s = 0; s < 8; ++s) {
                float dv = s == 0 ? d0 : s == 1 ? d1 : s == 2 ? d2 :
                           s == 3 ? d3 : s == 4 ? d4 : s == 5 ? d5 :
                           s == 6 ? d6 : d7;
                if (dv <= tau_f) {
                    unsigned u  = sortable_f32(dv);
                    unsigned lo = (u << 12) | (unsigned)(jg + jl + s);
                    unsigned hi = 0x43300000u | (u >> 20);
                    buf[cnt * 256 + tid] =
                        ((unsigned long long)hi << 32) | (unsigned long long)lo;
                    ++cnt;
                }
            }

            if (__any(cnt > BUFN - 8)) {
                // ---- flush: drain buffers through the f64 network ----
                for (int k = 0; k < BUFN; ++k) {
                    if (!__any(cnt > k)) break;     // early out (late flushes)
                    unsigned long long kb = buf[k * 256 + tid];
                    double key = (k < cnt) ? __longlong_as_double(kb)
                                           : __longlong_as_double(SENT_BITS);
#pragma unroll
                    for (int kk = KNN-1; kk > 0; --kk) {
                        double mn = fmin(kd[kk], key);
                        kd[kk] = fmax(kd[kk-1], mn);
                    }
                    kd[0] = fmin(kd[0], key);
                }
                cnt = 0;
                if (nflush < 3) {         // exact tau only while it matters
                    ++nflush;
                    double tmp[KNN];
#pragma unroll
                    for (int k = 0; k < KNN; ++k) tmp[k] = kd[k];
                    double h = tmp[0];
#pragma unroll
                    for (int r = 0; r < KNN; ++r) {
                        h = tmp[0];
#pragma unroll
                        for (int m = 1; m <= 8; m <<= 1)
                            h = fmin(h, __shfl_xor(h, m, LPQ));
                        bool own = (__double_as_longlong(tmp[0]) ==
                                    __double_as_longlong(h));
#pragma unroll
                        for (int t2 = 0; t2 < KNN-1; ++t2)
                            tmp[t2] = own ? tmp[t2+1] : tmp[t2];
                        tmp[KNN-1] = own ? __longlong_as_double(SENT_BITS)
                                         : tmp[KNN-1];
                    }
                    unsigned tau_u = (unsigned)((unsigned long long)
                                                __double_as_longlong(h) >> 12);
                    // unsortable: real d2 keys have top bit set
                    tau_f = __uint_as_float(tau_u ^ 0x80000000u);
                }
            }
        }
    }

    // final drain
    for (int k = 0; k < BUFN; ++k) {
        if (!__any(cnt > k)) break;
        unsigned long long kb = buf[k * 256 + tid];
        double key = (k < cnt) ? __longlong_as_double(kb)
                               : __longlong_as_double(SENT_BITS);
#pragma unroll
        for (int kk = KNN-1; kk > 0; --kk) {
            double mn = fmin(kd[kk], key);
            kd[kk] = fmax(kd[kk-1], mn);
        }
        kd[0] = fmin(kd[0], key);
    }

    // destructive 16-lane merge (r8 verbatim) -> res[] = original indices
    unsigned res[KNN];
#pragma unroll
    for (int r = 0; r < KNN; ++r) {
        double h = kd[0];
#pragma unroll
        for (int m = 1; m <= 8; m <<= 1)
            h = fmin(h, __shfl_xor(h, m, LPQ));
        long long hb = __double_as_longlong(h);
        res[r] = (unsigned)(hb & 0xFFF);
        bool own = (__double_as_longlong(kd[0]) == hb);
#pragma unroll
        for (int t = 0; t < KNN-1; ++t) kd[t] = own ? kd[t+1] : kd[t];
        kd[KNN-1] = own ? __longlong_as_double(SENT_BITS) : kd[KNN-1];
    }

    // ---------- fused MLP, lane-parallel, BIT-IDENTICAL to r8 ----------
    const float* vb = vel + (size_t)b * NPTS * 3;

    const float* w0 = W1 + (2*p)   * 66;
    const float* w1 = W1 + (2*p+1) * 66;
    float a0 = b1[2*p], a1 = b1[2*p+1];
#pragma unroll
    for (int k = 1; k < KNN; ++k) {       // ff 0..29: relative positions
        const float* pn = pb + 3*(int)res[k];
        float dx = pn[0] - xq, dy = pn[1] - yq, dz = pn[2] - zq;
        int ff = 3*(k-1);
        a0 = fmaf(dx, w0[ff+0], a0); a1 = fmaf(dx, w1[ff+0], a1);
        a0 = fmaf(dy, w0[ff+1], a0); a1 = fmaf(dy, w1[ff+1], a1);
        a0 = fmaf(dz, w0[ff+2], a0); a1 = fmaf(dz, w1[ff+2], a1);
    }
#pragma unroll
    for (int k = 0; k < KNN; ++k) {       // ff 30..62: velocities
        const float* vn = vb + 3*(int)res[k];
        int ff = 30 + 3*k;
        a0 = fmaf(vn[0], w0[ff+0], a0); a1 = fmaf(vn[0], w1[ff+0], a1);
        a0 = fmaf(vn[1], w0[ff+1], a0); a1 = fmaf(vn[1], w1[ff+1], a1);
        a0 = fmaf(vn[2], w0[ff+2], a0); a1 = fmaf(vn[2], w1[ff+2], a1);
    }
    float c0i = initc[b*3+0], c1i = initc[b*3+1], c2i = initc[b*3+2];
    a0 = fmaf(c0i, w0[63], a0); a1 = fmaf(c0i, w1[63], a1);
    a0 = fmaf(c1i, w0[64], a0); a1 = fmaf(c1i, w1[64], a1);
    a0 = fmaf(c2i, w0[65], a0); a1 = fmaf(c2i, w1[65], a1);

    float h2 = b2[p];
    const float* w2 = W2 + p * 32;
#pragma unroll
    for (int ii = 0; ii < 32; ++ii) {
        float h1v = __shfl((ii & 1) ? a1 : a0, ii >> 1, LPQ);
        h2 = fmaf(h1v, w2[ii], h2);
    }
    int o3 = p < 6 ? p : 0;
    float po = b3[o3];
    const float* w3 = W3 + o3 * 16;
#pragma unroll
    for (int ii = 0; ii < 16; ++ii) {
        float h2v = __shfl(h2, ii, LPQ);
        po = fmaf(h2v, w3[ii], po);
    }
    float resid = (p == 0) ? xq : (p == 1) ? yq : (p == 2) ? zq : 0.0f;
    po += resid;                           // residual on first 3 channels

    if (p < 6)
        out[((size_t)b * NPTS + (size_t)i) * 6 + p] = po;
}

extern "C" void kernel_launch(void* const* d_in, const int* in_sizes, int n_in,
                              void* d_out, int out_size, void* d_ws, size_t ws_size,
                              hipStream_t stream) {
    const float* pos   = (const float*)d_in[0];
    const float* vel   = (const float*)d_in[1];
    const float* initc = (const float*)d_in[2];
    const float* W1    = (const float*)d_in[3];
    const float* b1    = (const float*)d_in[4];
    const float* W2    = (const float*)d_in[5];
    const float* b2    = (const float*)d_in[6];
    const float* W3    = (const float*)d_in[7];
    const float* b3    = (const float*)d_in[8];
    float* out = (float*)d_out;

    fused_kernel<<<dim3(BATCH * (NPTS / QPB)), dim3(256), 0, stream>>>(
        pos, vel, initc, W1, b1, W2, b2, W3, b3, out);
}